// Round 1
// baseline (1115.426 us; speedup 1.0000x reference)
//
#include <hip/hip_runtime.h>

// GRU, 25 steps, UNITS=16, fed-back output (inp == h for steps >= 2).
// 16 lanes per row; lane owns unit u. Weights register-resident per lane
// (combined K+RK columns for z/r). h replicated across the 16-lane group;
// re-replication per step via 1 ds_write + 4 broadcast ds_read_b128,
// groups never span waves -> no __syncthreads anywhere.

#define UNITS 16
#define STEPS 25
#define ROWS_PER_BLOCK 16
#define BLOCK_THREADS 256

__device__ __forceinline__ float fast_rcp(float x)  { return __builtin_amdgcn_rcpf(x); }
__device__ __forceinline__ float fast_exp2(float x) { return __builtin_amdgcn_exp2f(x); }

__device__ __forceinline__ float fast_sigmoid(float x) {
    // 1 / (1 + exp(-x)) ; exp(-x) = 2^(-x*log2e). Saturates correctly via inf.
    return fast_rcp(1.0f + fast_exp2(x * -1.4426950408889634f));
}
__device__ __forceinline__ float fast_tanh(float x) {
    // 1 - 2/(1 + exp(2x))
    return 1.0f - 2.0f * fast_rcp(1.0f + fast_exp2(x * 2.8853900817779268f));
}

__global__ __launch_bounds__(BLOCK_THREADS, 4)
void gru_seq_kernel(const float* __restrict__ x,
                    const float* __restrict__ K,    // [16][48] z|r|h
                    const float* __restrict__ RK,   // [16][48]
                    const float* __restrict__ bias, // [2][48]  b_i | b_r
                    float* __restrict__ out,        // [B][25][16]
                    int B)
{
    __shared__ float lds_h[ROWS_PER_BLOCK * UNITS];   // 1 KiB

    const int tid = threadIdx.x;
    const int u   = tid & (UNITS - 1);
    const int g   = tid >> 4;
    const int row = blockIdx.x * ROWS_PER_BLOCK + g;
    const bool active = row < B;

    float* lds_grp = &lds_h[g * UNITS];

    // biases for own unit column
    const float bi_z = bias[u],          br_z = bias[48 + u];
    const float bi_r = bias[16 + u],     br_r = bias[48 + 16 + u];
    const float bi_h = bias[32 + u],     br_h = bias[48 + 32 + u];

    float h_my = active ? x[(size_t)row * UNITS + u] : 0.0f;

    float hrep[16];
    // replicate x across the 16-lane group (same wave -> ordered LDS, no barrier)
    {
        lds_grp[u] = h_my;
        float4 a = ((const float4*)lds_grp)[0];
        float4 b = ((const float4*)lds_grp)[1];
        float4 c = ((const float4*)lds_grp)[2];
        float4 d = ((const float4*)lds_grp)[3];
        hrep[0]=a.x; hrep[1]=a.y; hrep[2]=a.z; hrep[3]=a.w;
        hrep[4]=b.x; hrep[5]=b.y; hrep[6]=b.z; hrep[7]=b.w;
        hrep[8]=c.x; hrep[9]=c.y; hrep[10]=c.z; hrep[11]=c.w;
        hrep[12]=d.x; hrep[13]=d.y; hrep[14]=d.z; hrep[15]=d.w;
    }

    float* op = out + (size_t)row * (STEPS * UNITS) + u;

    // ---- step 0: inp = 0 (x_proj = b_i), h = x ----
    {
        float az = bi_z + br_z;
        float ar = bi_r + br_r;
        float ah = br_h;
        #pragma unroll
        for (int k = 0; k < 16; ++k) {
            float xk = hrep[k];
            az = fmaf(xk, RK[k*48 + u],      az);
            ar = fmaf(xk, RK[k*48 + 16 + u], ar);
            ah = fmaf(xk, RK[k*48 + 32 + u], ah);
        }
        float z  = fast_sigmoid(az);
        float r  = fast_sigmoid(ar);
        float hh = fast_tanh(fmaf(r, ah, bi_h));
        float hn = fmaf(z, h_my - hh, hh);   // z*h + (1-z)*hh
        if (active) op[0] = hn;
        h_my = hn;
    }

    // register-resident combined weight columns for steps >= 1 (inp == h)
    float Wz[16], Wr[16], Wh[16], Uh[16];
    #pragma unroll
    for (int k = 0; k < 16; ++k) {
        Wz[k] = K[k*48 + u]      + RK[k*48 + u];
        Wr[k] = K[k*48 + 16 + u] + RK[k*48 + 16 + u];
        Wh[k] = K[k*48 + 32 + u];
        Uh[k] = RK[k*48 + 32 + u];
    }
    const float bz = bi_z + br_z;
    const float brr = bi_r + br_r;

    for (int t = 1; t < STEPS; ++t) {
        // re-replicate h (write own, read group's 16) — same wave, in order
        lds_grp[u] = h_my;
        float4 a = ((const float4*)lds_grp)[0];
        float4 b = ((const float4*)lds_grp)[1];
        float4 c = ((const float4*)lds_grp)[2];
        float4 d = ((const float4*)lds_grp)[3];
        hrep[0]=a.x; hrep[1]=a.y; hrep[2]=a.z; hrep[3]=a.w;
        hrep[4]=b.x; hrep[5]=b.y; hrep[6]=b.z; hrep[7]=b.w;
        hrep[8]=c.x; hrep[9]=c.y; hrep[10]=c.z; hrep[11]=c.w;
        hrep[12]=d.x; hrep[13]=d.y; hrep[14]=d.z; hrep[15]=d.w;

        float az = bz, ar = brr, axh = bi_h, arh = br_h;
        #pragma unroll
        for (int k = 0; k < 16; ++k) {
            float hk = hrep[k];
            az  = fmaf(hk, Wz[k], az);
            ar  = fmaf(hk, Wr[k], ar);
            axh = fmaf(hk, Wh[k], axh);
            arh = fmaf(hk, Uh[k], arh);
        }
        float z  = fast_sigmoid(az);
        float r  = fast_sigmoid(ar);
        float hh = fast_tanh(fmaf(r, arh, axh));
        float hn = fmaf(z, h_my - hh, hh);
        if (active) op[t * UNITS] = hn;
        h_my = hn;
    }
}

extern "C" void kernel_launch(void* const* d_in, const int* in_sizes, int n_in,
                              void* d_out, int out_size, void* d_ws, size_t ws_size,
                              hipStream_t stream) {
    const float* x    = (const float*)d_in[0];
    const float* K    = (const float*)d_in[1];
    const float* RK   = (const float*)d_in[2];
    const float* bias = (const float*)d_in[3];
    float* out = (float*)d_out;

    const int B = in_sizes[0] / UNITS;
    const int grid = (B + ROWS_PER_BLOCK - 1) / ROWS_PER_BLOCK;
    gru_seq_kernel<<<grid, BLOCK_THREADS, 0, stream>>>(x, K, RK, bias, out, B);
}